// Round 7
// baseline (205.030 us; speedup 1.0000x reference)
//
#include <hip/hip_runtime.h>
#include <hip/hip_bf16.h>
#include <math.h>

// Top2Router — R7 DIAGNOSTIC round.
// R2-R6: five different structures (prefetch rings, LDS dbuf, split-K TLP)
// all pinned at kernel ~57-60us with zero kernel-level counter visibility
// (kernel < 77us top-5 cutoff; only the harness's 512MiB poison fills show).
// This round doubles K1's x-read (pass 2 into a dummy acc weighted by a
// runtime-zero, barrier-separated, output bit-identical) to:
//   1) push K1 over the top-5 cutoff -> get FETCH_SIZE / VALUBusy / occupancy
//   2) measure the marginal cost of a warm re-read of x (L3 residency test)
// Decision: warm pass cheap + FETCH~134MB + low VALUBusy => external
// contention floor (poison-fill writeback/eviction) => roofline case.
// Warm pass ~equal cost or high VALUBusy => internal limiter, fix that pipe.

#define NTOK  16384
#define DM    2048
#define NE    8
#define KS    8
#define KSF   (DM / KS)           // 256
#define PART_STRIDE (NTOK * NE)   // 131072

__device__ __forceinline__ float fold4(const float4 a) {
    return (a.x + a.y) + (a.z + a.w);
}

__device__ __forceinline__ float reduce_scatter8(const float4* acc, const int j) {
    float v0 = fold4(acc[0]), v1 = fold4(acc[1]), v2 = fold4(acc[2]), v3 = fold4(acc[3]);
    float v4 = fold4(acc[4]), v5 = fold4(acc[5]), v6 = fold4(acc[6]), v7 = fold4(acc[7]);
    float s0 = v0 + __shfl_xor(v0, 1, 8);
    float s1 = v1 + __shfl_xor(v1, 1, 8);
    float s2 = v2 + __shfl_xor(v2, 1, 8);
    float s3 = v3 + __shfl_xor(v3, 1, 8);
    float s4 = v4 + __shfl_xor(v4, 1, 8);
    float s5 = v5 + __shfl_xor(v5, 1, 8);
    float s6 = v6 + __shfl_xor(v6, 1, 8);
    float s7 = v7 + __shfl_xor(v7, 1, 8);
    const bool b0 = (j & 1);
    float t0 = b0 ? s1 : s0;
    float t1 = b0 ? s3 : s2;
    float t2 = b0 ? s5 : s4;
    float t3 = b0 ? s7 : s6;
    float p0 = t0 + __shfl_xor(t0, 2, 8);
    float p1 = t1 + __shfl_xor(t1, 2, 8);
    float p2 = t2 + __shfl_xor(t2, 2, 8);
    float p3 = t3 + __shfl_xor(t3, 2, 8);
    const bool b1 = (j & 2);
    float u0 = b1 ? p1 : p0;
    float u1 = b1 ? p3 : p2;
    float q0 = u0 + __shfl_xor(u0, 4, 8);
    float q1 = u1 + __shfl_xor(u1, 4, 8);
    return (j & 4) ? q1 : q0;
}

__device__ __forceinline__ void softmax_top2(const float logit, const int j,
                                             const int token, float* __restrict__ out) {
    float m = logit;
#pragma unroll
    for (int s = 4; s; s >>= 1) m = fmaxf(m, __shfl_xor(m, s, 8));
    const float ex = expf(logit - m);
    float sum = ex;
#pragma unroll
    for (int s = 4; s; s >>= 1) sum += __shfl_xor(sum, s, 8);
    const float gate = ex / sum;

    out[65536 + token * NE + j] = gate;

    float g1 = gate; int e1 = j;
#pragma unroll
    for (int s = 4; s; s >>= 1) {
        const float og = __shfl_xor(g1, s, 8);
        const int   oe = __shfl_xor(e1, s, 8);
        if (og > g1 || (og == g1 && oe < e1)) { g1 = og; e1 = oe; }
    }
    float g2 = (j == e1) ? -INFINITY : gate; int e2 = j;
#pragma unroll
    for (int s = 4; s; s >>= 1) {
        const float og = __shfl_xor(g2, s, 8);
        const int   oe = __shfl_xor(e2, s, 8);
        if (og > g2 || (og == g2 && oe < e2)) { g2 = og; e2 = oe; }
    }
    if (j == 0) {
        out[token * 2 + 0]         = g1;
        out[token * 2 + 1]         = g2;
        out[32768 + token * 2 + 0] = (float)e1;
        out[32768 + token * 2 + 1] = (float)e2;
    }
}

// ---- K1 (diagnostic): partial dots, x read TWICE (pass2 weight = runtime 0)
__global__ __launch_bounds__(256, 6) void router_partial_dbl(
    const float* __restrict__ x,
    const float* __restrict__ W,
    float* __restrict__ part)
{
    __shared__ __align__(16) float sW8[NE * KSF];   // 8 KB

    const int t     = threadIdx.x;
    const int chunk = blockIdx.x >> 3;
    const int ks    = blockIdx.x & 7;

    {
        const float4* __restrict__ Wv = reinterpret_cast<const float4*>(W);
        float4* sWv = reinterpret_cast<float4*>(sW8);
#pragma unroll
        for (int i = 0; i < 2; ++i) {
            const int idx = i * 256 + t;
            const int e   = idx >> 6;
            const int f4  = idx & 63;
            sWv[idx] = Wv[e * (DM / 4) + ks * (KSF / 4) + f4];
        }
    }
    __syncthreads();

    const int lane = t & 63;
    const int wave = t >> 6;
    const int j    = lane & 7;
    const int st   = lane >> 3;
    const int tok  = chunk * 32 + wave * 8 + st;

    const float* __restrict__ xp = x + (size_t)tok * DM + ks * KSF + (j << 2);

    float4 acc[NE];
#pragma unroll
    for (int e = 0; e < NE; ++e) acc[e] = make_float4(0.f, 0.f, 0.f, 0.f);

    // ---- pass 1 (real) ----
    {
        float4 xa = *reinterpret_cast<const float4*>(xp);
#pragma unroll
        for (int it = 0; it < 8; ++it) {
            float4 xn;
            if (it < 7) xn = *reinterpret_cast<const float4*>(xp + ((it + 1) << 5));
            const float* wbase = &sW8[(it << 5) + (j << 2)];
#pragma unroll
            for (int e = 0; e < NE; ++e) {
                const float4 wv = *reinterpret_cast<const float4*>(wbase + e * KSF);
                acc[e].x = fmaf(xa.x, wv.x, acc[e].x);
                acc[e].y = fmaf(xa.y, wv.y, acc[e].y);
                acc[e].z = fmaf(xa.z, wv.z, acc[e].z);
                acc[e].w = fmaf(xa.w, wv.w, acc[e].w);
            }
            xa = xn;
        }
    }
    const float preal = reduce_scatter8(acc, j);

    __syncthreads();   // phase separation: pass 2 cannot interleave with pass 1

    // ---- pass 2 (dummy, identical addresses; result weighted by runtime 0)
#pragma unroll
    for (int e = 0; e < NE; ++e) acc[e] = make_float4(0.f, 0.f, 0.f, 0.f);
    {
        float4 xa = *reinterpret_cast<const float4*>(xp);
#pragma unroll
        for (int it = 0; it < 8; ++it) {
            float4 xn;
            if (it < 7) xn = *reinterpret_cast<const float4*>(xp + ((it + 1) << 5));
            const float* wbase = &sW8[(it << 5) + (j << 2)];
#pragma unroll
            for (int e = 0; e < NE; ++e) {
                const float4 wv = *reinterpret_cast<const float4*>(wbase + e * KSF);
                acc[e].x = fmaf(xa.x, wv.x, acc[e].x);
                acc[e].y = fmaf(xa.y, wv.y, acc[e].y);
                acc[e].z = fmaf(xa.z, wv.z, acc[e].z);
                acc[e].w = fmaf(xa.w, wv.w, acc[e].w);
            }
            xa = xn;
        }
    }
    const float pdummy = reduce_scatter8(acc, j);

    // runtime zero: sW8[0] is finite uniform(-b,b); compiler cannot fold x*0
    const float zw = fminf(sW8[0] * 0.0f, 0.0f);

    part[(size_t)ks * PART_STRIDE + (size_t)tok * NE + j] = preal + zw * pdummy;
}

// ---- K2: reduce slices + softmax + top2 (unchanged, verified) ----
__global__ __launch_bounds__(256) void router_final(
    const float* __restrict__ part,
    const float* __restrict__ b,
    float* __restrict__ out)
{
    const int t    = threadIdx.x;
    const int lane = t & 63;
    const int wave = t >> 6;
    const int j    = lane & 7;
    const int st   = lane >> 3;
    const int tok  = blockIdx.x * 32 + wave * 8 + st;

    const size_t base = (size_t)tok * NE + j;
    float s = 0.f;
#pragma unroll
    for (int ks = 0; ks < KS; ++ks)
        s += part[(size_t)ks * PART_STRIDE + base];

    const float logit = s + b[j];
    softmax_top2(logit, j, tok, out);
}

extern "C" void kernel_launch(void* const* d_in, const int* in_sizes, int n_in,
                              void* d_out, int out_size, void* d_ws, size_t ws_size,
                              hipStream_t stream) {
    const float* x = (const float*)d_in[0];
    const float* W = (const float*)d_in[1];
    const float* b = (const float*)d_in[2];
    float* out  = (float*)d_out;
    float* part = (float*)d_ws;   // 4 MB used, fully overwritten by K1

    router_partial_dbl<<<4096, 256, 0, stream>>>(x, W, part);
    router_final<<<512, 256, 0, stream>>>(part, b, out);
}

// Round 8
// 185.021 us; speedup vs baseline: 1.1081x; 1.1081x over previous
//
#include <hip/hip_runtime.h>
#include <hip/hip_bf16.h>
#include <math.h>

// Top2Router — R8: split-K (R6 structure) + NON-TEMPORAL x loads.
// R7 diagnostic: a warm second pass over x cost +11.6us (11.5 TB/s) vs the
// 57us first pass (2.3 TB/s) -> limiter is NOT issue rate; it's dirty-cache
// displacement: the harness's 512MiB poison fill + x-restore leave L3 full of
// dirty lines, and every cold x miss forces a dirty writeback (~200MB) onto
// our critical path. Fix: nt loads for x -> streaming misses don't displace
// dirty lines (victimize our own clean NT lines), writeback leaves the
// critical path. L3-resident half of x still hits (nt affects allocation,
// not lookup). Expected kernel ~20-30us vs 57us.

#define NTOK  16384
#define DM    2048
#define NE    8
#define KS    8
#define KSF   (DM / KS)           // 256
#define PART_STRIDE (NTOK * NE)   // 131072

typedef float v4f __attribute__((ext_vector_type(4)));

__device__ __forceinline__ float fold4(const float4 a) {
    return (a.x + a.y) + (a.z + a.w);
}

// Reduce-scatter 8 per-lane expert partials across the 8 j-lanes of a token:
// returns the dot for expert e == j. (Verified R2-R7.)
__device__ __forceinline__ float reduce_scatter8(const float4* acc, const int j) {
    float v0 = fold4(acc[0]), v1 = fold4(acc[1]), v2 = fold4(acc[2]), v3 = fold4(acc[3]);
    float v4 = fold4(acc[4]), v5 = fold4(acc[5]), v6 = fold4(acc[6]), v7 = fold4(acc[7]);
    float s0 = v0 + __shfl_xor(v0, 1, 8);
    float s1 = v1 + __shfl_xor(v1, 1, 8);
    float s2 = v2 + __shfl_xor(v2, 1, 8);
    float s3 = v3 + __shfl_xor(v3, 1, 8);
    float s4 = v4 + __shfl_xor(v4, 1, 8);
    float s5 = v5 + __shfl_xor(v5, 1, 8);
    float s6 = v6 + __shfl_xor(v6, 1, 8);
    float s7 = v7 + __shfl_xor(v7, 1, 8);
    const bool b0 = (j & 1);
    float t0 = b0 ? s1 : s0;
    float t1 = b0 ? s3 : s2;
    float t2 = b0 ? s5 : s4;
    float t3 = b0 ? s7 : s6;
    float p0 = t0 + __shfl_xor(t0, 2, 8);
    float p1 = t1 + __shfl_xor(t1, 2, 8);
    float p2 = t2 + __shfl_xor(t2, 2, 8);
    float p3 = t3 + __shfl_xor(t3, 2, 8);
    const bool b1 = (j & 2);
    float u0 = b1 ? p1 : p0;
    float u1 = b1 ? p3 : p2;
    float q0 = u0 + __shfl_xor(u0, 4, 8);
    float q1 = u1 + __shfl_xor(u1, 4, 8);
    return (j & 4) ? q1 : q0;
}

// 8-lane softmax + top2 epilogue for one token. (Verified R1-R7.)
__device__ __forceinline__ void softmax_top2(const float logit, const int j,
                                             const int token, float* __restrict__ out) {
    float m = logit;
#pragma unroll
    for (int s = 4; s; s >>= 1) m = fmaxf(m, __shfl_xor(m, s, 8));
    const float ex = expf(logit - m);
    float sum = ex;
#pragma unroll
    for (int s = 4; s; s >>= 1) sum += __shfl_xor(sum, s, 8);
    const float gate = ex / sum;

    out[65536 + token * NE + j] = gate;

    float g1 = gate; int e1 = j;
#pragma unroll
    for (int s = 4; s; s >>= 1) {
        const float og = __shfl_xor(g1, s, 8);
        const int   oe = __shfl_xor(e1, s, 8);
        if (og > g1 || (og == g1 && oe < e1)) { g1 = og; e1 = oe; }
    }
    float g2 = (j == e1) ? -INFINITY : gate; int e2 = j;
#pragma unroll
    for (int s = 4; s; s >>= 1) {
        const float og = __shfl_xor(g2, s, 8);
        const int   oe = __shfl_xor(e2, s, 8);
        if (og > g2 || (og == g2 && oe < e2)) { g2 = og; e2 = oe; }
    }
    if (j == 0) {
        out[token * 2 + 0]         = g1;
        out[token * 2 + 1]         = g2;
        out[32768 + token * 2 + 0] = (float)e1;
        out[32768 + token * 2 + 1] = (float)e2;
    }
}

// ---------------- Kernel 1: partial dots over one k-slice ----------------
// grid: 512 token-chunks x 8 k-slices = 4096 blocks, 256 threads.
// Each wave handles 8 tokens (lane = st*8+j), k-range = 256 floats.
__global__ __launch_bounds__(256, 6) void router_partial(
    const float* __restrict__ x,
    const float* __restrict__ W,
    float* __restrict__ part)
{
    __shared__ __align__(16) float sW8[NE * KSF];   // 8 KB

    const int t     = threadIdx.x;
    const int chunk = blockIdx.x >> 3;   // 0..511 (32 tokens each)
    const int ks    = blockIdx.x & 7;    // k-slice

    // stage W slice: W[e][ks*256 .. +256) -> sW8[e*256 ..). 512 float4s.
    {
        const float4* __restrict__ Wv = reinterpret_cast<const float4*>(W);
        float4* sWv = reinterpret_cast<float4*>(sW8);
#pragma unroll
        for (int i = 0; i < 2; ++i) {
            const int idx = i * 256 + t;
            const int e   = idx >> 6;
            const int f4  = idx & 63;
            sWv[idx] = Wv[e * (DM / 4) + ks * (KSF / 4) + f4];
        }
    }
    __syncthreads();

    const int lane = t & 63;
    const int wave = t >> 6;
    const int j    = lane & 7;
    const int st   = lane >> 3;
    const int tok  = chunk * 32 + wave * 8 + st;

    const float* __restrict__ xp = x + (size_t)tok * DM + ks * KSF + (j << 2);

    float4 acc[NE];
#pragma unroll
    for (int e = 0; e < NE; ++e) acc[e] = make_float4(0.f, 0.f, 0.f, 0.f);

    // 8 iterations of 32 floats; depth-2 prefetch; NT loads for x.
    v4f xa = __builtin_nontemporal_load(reinterpret_cast<const v4f*>(xp));
#pragma unroll
    for (int it = 0; it < 8; ++it) {
        v4f xn;
        if (it < 7)
            xn = __builtin_nontemporal_load(
                reinterpret_cast<const v4f*>(xp + ((it + 1) << 5)));
        const float* wbase = &sW8[(it << 5) + (j << 2)];
#pragma unroll
        for (int e = 0; e < NE; ++e) {
            const float4 wv = *reinterpret_cast<const float4*>(wbase + e * KSF);
            acc[e].x = fmaf(xa.x, wv.x, acc[e].x);
            acc[e].y = fmaf(xa.y, wv.y, acc[e].y);
            acc[e].z = fmaf(xa.z, wv.z, acc[e].z);
            acc[e].w = fmaf(xa.w, wv.w, acc[e].w);
        }
        xa = xn;
    }

    const float p = reduce_scatter8(acc, j);
    // lanes of a wave write 64 contiguous floats -> one coalesced store
    part[(size_t)ks * PART_STRIDE + (size_t)tok * NE + j] = p;
}

// ---------------- Kernel 2: reduce slices + softmax + top2 ----------------
__global__ __launch_bounds__(256) void router_final(
    const float* __restrict__ part,
    const float* __restrict__ b,
    float* __restrict__ out)
{
    const int t    = threadIdx.x;
    const int lane = t & 63;
    const int wave = t >> 6;
    const int j    = lane & 7;
    const int st   = lane >> 3;
    const int tok  = blockIdx.x * 32 + wave * 8 + st;

    const size_t base = (size_t)tok * NE + j;
    float s = 0.f;
#pragma unroll
    for (int ks = 0; ks < KS; ++ks)
        s += part[(size_t)ks * PART_STRIDE + base];

    const float logit = s + b[j];
    softmax_top2(logit, j, tok, out);
}

extern "C" void kernel_launch(void* const* d_in, const int* in_sizes, int n_in,
                              void* d_out, int out_size, void* d_ws, size_t ws_size,
                              hipStream_t stream) {
    const float* x = (const float*)d_in[0];
    const float* W = (const float*)d_in[1];
    const float* b = (const float*)d_in[2];
    float* out  = (float*)d_out;
    float* part = (float*)d_ws;   // 4 MB used, fully overwritten by K1

    router_partial<<<4096, 256, 0, stream>>>(x, W, part);
    router_final<<<512, 256, 0, stream>>>(part, b, out);
}

// Round 9
// 183.706 us; speedup vs baseline: 1.1161x; 1.0072x over previous
//
#include <hip/hip_runtime.h>
#include <hip/hip_bf16.h>
#include <math.h>

// Top2Router — R9: single fused kernel, split-K ACROSS WAVES + NT x loads.
// R8 established: limiter is external dirty-cache displacement (harness's
// 512MiB poison fill + x-restore leave L3 full of dirty lines; its writeback
// drains on our critical path). NT loads cut kernel 57->49us. Remaining
// addressable overhead: K2's 4MB part round-trip + launch gap + per-block
// W-staging barrier phase-lock. Fix: fuse. Block = 16 tokens x full D;
// wave w owns k-quarter [w*512,(w+1)*512): stages its own 16KB W-quarter
// (no barrier - same-wave LDS RAW ordered by lgkmcnt), accumulates
// 16 tok x 8 exp partials, writes 2KB to LDS; ONE __syncthreads; waves 0-1
// reduce 4 partials + bias -> verified softmax/top2 epilogue.
// 66KB LDS -> 2 blocks/CU, 8 decorrelated waves/CU. 1024 blocks.

#define NTOK  16384
#define DM    2048
#define NE    8
#define TPB   16            // tokens per block
#define KQ    512           // k-quarter per wave (floats)

typedef float v4f __attribute__((ext_vector_type(4)));

__device__ __forceinline__ float fold4(const float4 a) {
    return (a.x + a.y) + (a.z + a.w);
}

// Reduce-scatter 8 per-lane expert partials across the 8 j-lanes of a token:
// lane j returns the (k-quarter) dot for expert e == j. (Verified R2-R8.)
__device__ __forceinline__ float reduce_scatter8(const float4* acc, const int j) {
    float v0 = fold4(acc[0]), v1 = fold4(acc[1]), v2 = fold4(acc[2]), v3 = fold4(acc[3]);
    float v4 = fold4(acc[4]), v5 = fold4(acc[5]), v6 = fold4(acc[6]), v7 = fold4(acc[7]);
    float s0 = v0 + __shfl_xor(v0, 1, 8);
    float s1 = v1 + __shfl_xor(v1, 1, 8);
    float s2 = v2 + __shfl_xor(v2, 1, 8);
    float s3 = v3 + __shfl_xor(v3, 1, 8);
    float s4 = v4 + __shfl_xor(v4, 1, 8);
    float s5 = v5 + __shfl_xor(v5, 1, 8);
    float s6 = v6 + __shfl_xor(v6, 1, 8);
    float s7 = v7 + __shfl_xor(v7, 1, 8);
    const bool b0 = (j & 1);
    float t0 = b0 ? s1 : s0;
    float t1 = b0 ? s3 : s2;
    float t2 = b0 ? s5 : s4;
    float t3 = b0 ? s7 : s6;
    float p0 = t0 + __shfl_xor(t0, 2, 8);
    float p1 = t1 + __shfl_xor(t1, 2, 8);
    float p2 = t2 + __shfl_xor(t2, 2, 8);
    float p3 = t3 + __shfl_xor(t3, 2, 8);
    const bool b1 = (j & 2);
    float u0 = b1 ? p1 : p0;
    float u1 = b1 ? p3 : p2;
    float q0 = u0 + __shfl_xor(u0, 4, 8);
    float q1 = u1 + __shfl_xor(u1, 4, 8);
    return (j & 4) ? q1 : q0;
}

// 8-lane softmax + top2 epilogue for one token. (Verified R1-R8.)
__device__ __forceinline__ void softmax_top2(const float logit, const int j,
                                             const int token, float* __restrict__ out) {
    float m = logit;
#pragma unroll
    for (int s = 4; s; s >>= 1) m = fmaxf(m, __shfl_xor(m, s, 8));
    const float ex = expf(logit - m);
    float sum = ex;
#pragma unroll
    for (int s = 4; s; s >>= 1) sum += __shfl_xor(sum, s, 8);
    const float gate = ex / sum;

    out[65536 + token * NE + j] = gate;

    float g1 = gate; int e1 = j;
#pragma unroll
    for (int s = 4; s; s >>= 1) {
        const float og = __shfl_xor(g1, s, 8);
        const int   oe = __shfl_xor(e1, s, 8);
        if (og > g1 || (og == g1 && oe < e1)) { g1 = og; e1 = oe; }
    }
    float g2 = (j == e1) ? -INFINITY : gate; int e2 = j;
#pragma unroll
    for (int s = 4; s; s >>= 1) {
        const float og = __shfl_xor(g2, s, 8);
        const int   oe = __shfl_xor(e2, s, 8);
        if (og > g2 || (og == g2 && oe < e2)) { g2 = og; e2 = oe; }
    }
    if (j == 0) {
        out[token * 2 + 0]         = g1;
        out[token * 2 + 1]         = g2;
        out[32768 + token * 2 + 0] = (float)e1;
        out[32768 + token * 2 + 1] = (float)e2;
    }
}

__global__ __launch_bounds__(256, 2) void router_fused(
    const float* __restrict__ x,
    const float* __restrict__ W,
    const float* __restrict__ b,
    float* __restrict__ out)
{
    __shared__ __align__(16) float sWq[4 * NE * KQ];  // 4 waves x 16KB = 64KB
    __shared__ float sPart[4 * TPB * NE];             // 4 x 128 floats = 2KB

    const int t    = threadIdx.x;
    const int wv   = t >> 6;
    const int lane = t & 63;
    const int j    = lane & 7;
    const int st   = lane >> 3;

    // ---- wave wv stages its own W k-quarter: W[e][wv*512 .. +512) ----
    // 1024 float4 per quarter, 16 per lane; lanes consecutive -> coalesced.
    {
        const float4* __restrict__ Wv = reinterpret_cast<const float4*>(W);
        float4* sWv = reinterpret_cast<float4*>(&sWq[wv * NE * KQ]);
#pragma unroll
        for (int i = 0; i < 16; ++i) {
            const int L  = i * 64 + lane;      // 0..1023
            const int e  = L >> 7;             // 128 float4 per expert-quarter
            const int f4 = L & 127;
            sWv[L] = Wv[e * (DM / 4) + wv * (KQ / 4) + f4];
        }
    }
    // NO barrier: this wave reads only the region it wrote (lgkmcnt-ordered).

    const int tokbase = blockIdx.x * TPB;
    const int tok0 = tokbase + st;
    const int tok1 = tokbase + st + 8;
    const float* __restrict__ xp0 = x + (size_t)tok0 * DM + wv * KQ + (j << 2);
    const float* __restrict__ xp1 = x + (size_t)tok1 * DM + wv * KQ + (j << 2);

    float4 acc0[NE], acc1[NE];
#pragma unroll
    for (int e = 0; e < NE; ++e) {
        acc0[e] = make_float4(0.f, 0.f, 0.f, 0.f);
        acc1[e] = make_float4(0.f, 0.f, 0.f, 0.f);
    }

    // ---- k-loop: 16 iters x 32 floats over this wave's quarter; NT loads,
    //      depth-1 prefetch (TLP from 8 decorrelated waves/CU does the rest).
    v4f xa0 = __builtin_nontemporal_load(reinterpret_cast<const v4f*>(xp0));
    v4f xa1 = __builtin_nontemporal_load(reinterpret_cast<const v4f*>(xp1));
#pragma unroll
    for (int it = 0; it < 16; ++it) {
        v4f xn0, xn1;
        if (it < 15) {
            xn0 = __builtin_nontemporal_load(
                reinterpret_cast<const v4f*>(xp0 + ((it + 1) << 5)));
            xn1 = __builtin_nontemporal_load(
                reinterpret_cast<const v4f*>(xp1 + ((it + 1) << 5)));
        }
        const float* wbase = &sWq[wv * NE * KQ + (it << 5) + (j << 2)];
#pragma unroll
        for (int e = 0; e < NE; ++e) {
            const float4 wvv = *reinterpret_cast<const float4*>(wbase + e * KQ);
            acc0[e].x = fmaf(xa0.x, wvv.x, acc0[e].x);
            acc0[e].y = fmaf(xa0.y, wvv.y, acc0[e].y);
            acc0[e].z = fmaf(xa0.z, wvv.z, acc0[e].z);
            acc0[e].w = fmaf(xa0.w, wvv.w, acc0[e].w);
            acc1[e].x = fmaf(xa1.x, wvv.x, acc1[e].x);
            acc1[e].y = fmaf(xa1.y, wvv.y, acc1[e].y);
            acc1[e].z = fmaf(xa1.z, wvv.z, acc1[e].z);
            acc1[e].w = fmaf(xa1.w, wvv.w, acc1[e].w);
        }
        xa0 = xn0;
        xa1 = xn1;
    }

    // ---- per-wave partials -> LDS ----
    const float p0 = reduce_scatter8(acc0, j);   // expert j, token st
    const float p1 = reduce_scatter8(acc1, j);   // expert j, token st+8
    sPart[wv * (TPB * NE) + st * NE + j]       = p0;
    sPart[wv * (TPB * NE) + (st + 8) * NE + j] = p1;
    __syncthreads();   // the ONE barrier

    // ---- waves 0-1: cross-wave reduce + softmax/top2 for 8 tokens each ----
    if (wv < 2) {
        const int tk   = wv * 8 + st;           // block-local token 0..15
        const int gtok = tokbase + tk;
        float s = sPart[0 * (TPB * NE) + tk * NE + j]
                + sPart[1 * (TPB * NE) + tk * NE + j]
                + sPart[2 * (TPB * NE) + tk * NE + j]
                + sPart[3 * (TPB * NE) + tk * NE + j];
        const float logit = s + b[j];
        softmax_top2(logit, j, gtok, out);
    }
}

extern "C" void kernel_launch(void* const* d_in, const int* in_sizes, int n_in,
                              void* d_out, int out_size, void* d_ws, size_t ws_size,
                              hipStream_t stream) {
    const float* x = (const float*)d_in[0];
    const float* W = (const float*)d_in[1];
    const float* b = (const float*)d_in[2];
    float* out = (float*)d_out;

    // 16 tokens/block, 1024 blocks; 66KB LDS -> 2 blocks/CU resident.
    router_fused<<<NTOK / TPB, 256, 0, stream>>>(x, W, b, out);
}

// Round 10
// 181.779 us; speedup vs baseline: 1.1279x; 1.0106x over previous
//
#include <hip/hip_runtime.h>
#include <hip/hip_bf16.h>
#include <math.h>

// Top2Router — R10: fused kernel, split-K across waves, T=4 tokens/lane.
// Ledger: kernel 57 -> 49 (NT loads) -> 48us (fusion); overhead 135.5us
// (validated vs R1 rocprof). Remaining internal cost: LDS pipe ~10us
// (2048 ds_read_b128/CU) + latency cover. This round: A=4 tokens per W-read
// -> per-CU ds_read halves (~5us), per-wave in-flight x doubles (32KB/CU).
// Block = 32 tokens; wave w owns k-quarter [w*512,(w+1)*512); lane=st*8+j
// handles tokens {st, st+8, st+16, st+24}. 512 blocks, 2/CU, one generation.
// If this is neutral (<2us), the kernel is pinned by harness-degraded memory
// service (cold streams run at ~2.6 TB/s here - AMD's own copyBuffer rate)
// and the next step is declaring the roofline.

#define NTOK  16384
#define DM    2048
#define NE    8
#define TPB   32            // tokens per block
#define KQ    512           // k-quarter per wave (floats)
#define TG    4             // token-groups per lane

typedef float v4f __attribute__((ext_vector_type(4)));

__device__ __forceinline__ float fold4(const float4 a) {
    return (a.x + a.y) + (a.z + a.w);
}

// Reduce-scatter 8 per-lane expert partials across the 8 j-lanes of a token:
// lane j returns the (k-quarter) dot for expert e == j. (Verified R2-R9.)
__device__ __forceinline__ float reduce_scatter8(const float4* acc, const int j) {
    float v0 = fold4(acc[0]), v1 = fold4(acc[1]), v2 = fold4(acc[2]), v3 = fold4(acc[3]);
    float v4 = fold4(acc[4]), v5 = fold4(acc[5]), v6 = fold4(acc[6]), v7 = fold4(acc[7]);
    float s0 = v0 + __shfl_xor(v0, 1, 8);
    float s1 = v1 + __shfl_xor(v1, 1, 8);
    float s2 = v2 + __shfl_xor(v2, 1, 8);
    float s3 = v3 + __shfl_xor(v3, 1, 8);
    float s4 = v4 + __shfl_xor(v4, 1, 8);
    float s5 = v5 + __shfl_xor(v5, 1, 8);
    float s6 = v6 + __shfl_xor(v6, 1, 8);
    float s7 = v7 + __shfl_xor(v7, 1, 8);
    const bool b0 = (j & 1);
    float t0 = b0 ? s1 : s0;
    float t1 = b0 ? s3 : s2;
    float t2 = b0 ? s5 : s4;
    float t3 = b0 ? s7 : s6;
    float p0 = t0 + __shfl_xor(t0, 2, 8);
    float p1 = t1 + __shfl_xor(t1, 2, 8);
    float p2 = t2 + __shfl_xor(t2, 2, 8);
    float p3 = t3 + __shfl_xor(t3, 2, 8);
    const bool b1 = (j & 2);
    float u0 = b1 ? p1 : p0;
    float u1 = b1 ? p3 : p2;
    float q0 = u0 + __shfl_xor(u0, 4, 8);
    float q1 = u1 + __shfl_xor(u1, 4, 8);
    return (j & 4) ? q1 : q0;
}

// 8-lane softmax + top2 epilogue for one token. (Verified R1-R9.)
__device__ __forceinline__ void softmax_top2(const float logit, const int j,
                                             const int token, float* __restrict__ out) {
    float m = logit;
#pragma unroll
    for (int s = 4; s; s >>= 1) m = fmaxf(m, __shfl_xor(m, s, 8));
    const float ex = expf(logit - m);
    float sum = ex;
#pragma unroll
    for (int s = 4; s; s >>= 1) sum += __shfl_xor(sum, s, 8);
    const float gate = ex / sum;

    out[65536 + token * NE + j] = gate;

    float g1 = gate; int e1 = j;
#pragma unroll
    for (int s = 4; s; s >>= 1) {
        const float og = __shfl_xor(g1, s, 8);
        const int   oe = __shfl_xor(e1, s, 8);
        if (og > g1 || (og == g1 && oe < e1)) { g1 = og; e1 = oe; }
    }
    float g2 = (j == e1) ? -INFINITY : gate; int e2 = j;
#pragma unroll
    for (int s = 4; s; s >>= 1) {
        const float og = __shfl_xor(g2, s, 8);
        const int   oe = __shfl_xor(e2, s, 8);
        if (og > g2 || (og == g2 && oe < e2)) { g2 = og; e2 = oe; }
    }
    if (j == 0) {
        out[token * 2 + 0]         = g1;
        out[token * 2 + 1]         = g2;
        out[32768 + token * 2 + 0] = (float)e1;
        out[32768 + token * 2 + 1] = (float)e2;
    }
}

__global__ __launch_bounds__(256, 2) void router_fused(
    const float* __restrict__ x,
    const float* __restrict__ W,
    const float* __restrict__ b,
    float* __restrict__ out)
{
    __shared__ __align__(16) float sWq[4 * NE * KQ];   // 4 waves x 16KB = 64KB
    __shared__ float sPart[4 * TPB * NE];              // 4 x 256 floats = 4KB

    const int t    = threadIdx.x;
    const int wv   = t >> 6;
    const int lane = t & 63;
    const int j    = lane & 7;
    const int st   = lane >> 3;

    // ---- wave wv stages its own W k-quarter: W[e][wv*512 .. +512) ----
    {
        const float4* __restrict__ Wv = reinterpret_cast<const float4*>(W);
        float4* sWv = reinterpret_cast<float4*>(&sWq[wv * NE * KQ]);
#pragma unroll
        for (int i = 0; i < 16; ++i) {
            const int L  = i * 64 + lane;      // 0..1023
            const int e  = L >> 7;             // 128 float4 per expert-quarter
            const int f4 = L & 127;
            sWv[L] = Wv[e * (DM / 4) + wv * (KQ / 4) + f4];
        }
    }
    // No barrier: this wave reads only the region it wrote (lgkmcnt-ordered).

    const int tokbase = blockIdx.x * TPB;

    const float* __restrict__ xp[TG];
#pragma unroll
    for (int g = 0; g < TG; ++g)
        xp[g] = x + (size_t)(tokbase + st + 8 * g) * DM + wv * KQ + (j << 2);

    float4 acc[TG][NE];
#pragma unroll
    for (int g = 0; g < TG; ++g)
#pragma unroll
        for (int e = 0; e < NE; ++e)
            acc[g][e] = make_float4(0.f, 0.f, 0.f, 0.f);

    // ---- k-loop: 16 iters x 32 floats; NT loads, depth-1 prefetch ----
    v4f xa[TG];
#pragma unroll
    for (int g = 0; g < TG; ++g)
        xa[g] = __builtin_nontemporal_load(reinterpret_cast<const v4f*>(xp[g]));

#pragma unroll
    for (int it = 0; it < 16; ++it) {
        v4f xn[TG];
        if (it < 15) {
#pragma unroll
            for (int g = 0; g < TG; ++g)
                xn[g] = __builtin_nontemporal_load(
                    reinterpret_cast<const v4f*>(xp[g] + ((it + 1) << 5)));
        }
        const float* wbase = &sWq[wv * NE * KQ + (it << 5) + (j << 2)];
#pragma unroll
        for (int e = 0; e < NE; ++e) {
            const float4 wvv = *reinterpret_cast<const float4*>(wbase + e * KQ);
#pragma unroll
            for (int g = 0; g < TG; ++g) {
                acc[g][e].x = fmaf(xa[g].x, wvv.x, acc[g][e].x);
                acc[g][e].y = fmaf(xa[g].y, wvv.y, acc[g][e].y);
                acc[g][e].z = fmaf(xa[g].z, wvv.z, acc[g][e].z);
                acc[g][e].w = fmaf(xa[g].w, wvv.w, acc[g][e].w);
            }
        }
#pragma unroll
        for (int g = 0; g < TG; ++g) xa[g] = xn[g];
    }

    // ---- per-wave partials -> LDS ----
#pragma unroll
    for (int g = 0; g < TG; ++g) {
        const float p = reduce_scatter8(acc[g], j);    // expert j, token st+8g
        sPart[wv * (TPB * NE) + (st + 8 * g) * NE + j] = p;
    }
    __syncthreads();   // the ONE barrier

    // ---- all 4 waves: cross-wave reduce + softmax/top2, 8 tokens each ----
    {
        const int tk   = wv * 8 + st;            // block-local token 0..31
        const int gtok = tokbase + tk;
        float s = sPart[0 * (TPB * NE) + tk * NE + j]
                + sPart[1 * (TPB * NE) + tk * NE + j]
                + sPart[2 * (TPB * NE) + tk * NE + j]
                + sPart[3 * (TPB * NE) + tk * NE + j];
        const float logit = s + b[j];
        softmax_top2(logit, j, gtok, out);
    }
}

extern "C" void kernel_launch(void* const* d_in, const int* in_sizes, int n_in,
                              void* d_out, int out_size, void* d_ws, size_t ws_size,
                              hipStream_t stream) {
    const float* x = (const float*)d_in[0];
    const float* W = (const float*)d_in[1];
    const float* b = (const float*)d_in[2];
    float* out = (float*)d_out;

    // 32 tokens/block, 512 blocks; 68KB LDS -> 2 blocks/CU, one generation.
    router_fused<<<NTOK / TPB, 256, 0, stream>>>(x, W, b, out);
}